// Round 3
// baseline (203.707 us; speedup 1.0000x reference)
//
#include <hip/hip_runtime.h>
#include <stdint.h>

// Haar 3D DWT: float32 in, float32 out, fp32 internal math.
// x: (2,3,16,256,256) f32
// out: LLL (2,3,15,256,256) followed by detail (2,3,105,256,256), f32.
// detail frame-axis order: LLH, LHL, LHH, HLL, HLH, HHL, HHH (15 frames each).
//
// V2b (V2 with compile fix): __builtin_nontemporal_store needs a native clang
// vector type, not HIP's float4 class — use ext_vector_type(4) float.
//  - one thread computes a vertical PAIR of output rows (h, h+1)
//  - 6 float4 loads per thread (rows h..h+2 of frames f,f+1) instead of 8
//  - per stream: two adjacent 1KB-contiguous wave stores = 2KB contiguous
//  - all output stores nontemporal (write-once data; keep L2 for the input)

static constexpr float S = 0.35355339059327373f;  // 1/(2*sqrt(2))
static constexpr int   PLANE = 256 * 256;          // 65536
static constexpr size_t LLL_ELEMS = (size_t)6 * 15 * PLANE;  // 5,898,240

typedef float f32x4 __attribute__((ext_vector_type(4)));

__device__ __forceinline__ f32x4 pack_lo(const float* A) {
    // width low-pass: S*(A[j] + A[j+1])
    f32x4 r;
    r.x = S * (A[0] + A[1]);
    r.y = S * (A[1] + A[2]);
    r.z = S * (A[2] + A[3]);
    r.w = S * (A[3] + A[4]);
    return r;
}

__device__ __forceinline__ f32x4 pack_hi(const float* A) {
    // width high-pass: S*(A[j+1] - A[j])
    f32x4 r;
    r.x = S * (A[1] - A[0]);
    r.y = S * (A[2] - A[1]);
    r.z = S * (A[3] - A[2]);
    r.w = S * (A[4] - A[3]);
    return r;
}

__device__ __forceinline__ void nt_store(float* p, f32x4 v) {
    __builtin_nontemporal_store(v, (f32x4*)p);
}

__global__ __launch_bounds__(256) void haar3d_kernel(const float* __restrict__ x,
                                                     float* __restrict__ out) {
    const int tid  = blockIdx.x * 256 + threadIdx.x;
    const int lane = threadIdx.x & 63;
    const int pr   = tid >> 6;          // pair-row id: 0..11519  (one wave per pair)
    const int h    = (pr & 127) << 1;   // 0,2,...,254 (pair = rows h, h+1; never crosses a frame)
    const int t    = pr >> 7;           // 0..89
    const int f    = t % 15;
    const int nc   = t / 15;            // 0..5  (n*3 + c)
    const int w    = lane << 2;

    // ---- loads: 6 rows of float4 (rows h,h+1,h+2 x frames f,f+1) ----
    const float* p00 = x + ((size_t)(nc * 16 + f) * 256 + h) * 256 + w;
    const f32x4 z4 = (f32x4)0.f;
    f32x4 v00 = *(const f32x4*)(p00);                 // (f,   h)
    f32x4 v10 = *(const f32x4*)(p00 + PLANE);         // (f+1, h)
    f32x4 v01 = *(const f32x4*)(p00 + 256);           // (f,   h+1)
    f32x4 v11 = *(const f32x4*)(p00 + PLANE + 256);   // (f+1, h+1)
    f32x4 v02 = z4, v12 = z4;                         // (*, h+2); zero-pad past 255
    if (h < 254) {                                    // wave-uniform branch
        v02 = *(const f32x4*)(p00 + 512);
        v12 = *(const f32x4*)(p00 + PLANE + 512);
    }

    const float x00[4] = {v00.x, v00.y, v00.z, v00.w};
    const float x10[4] = {v10.x, v10.y, v10.z, v10.w};
    const float x01[4] = {v01.x, v01.y, v01.z, v01.w};
    const float x11[4] = {v11.x, v11.y, v11.z, v11.w};
    const float x02[4] = {v02.x, v02.y, v02.z, v02.w};
    const float x12[4] = {v12.x, v12.y, v12.z, v12.w};

    // ---- frames + height stages (fp32), two output rows ----
    float LL0[5], LH0[5], HL0[5], HH0[5];
    float LL1[5], LH1[5], HL1[5], HH1[5];
#pragma unroll
    for (int j = 0; j < 4; ++j) {
        const float l0 = S * (x00[j] + x10[j]);   // frames low  @ h
        const float g0 = S * (x10[j] - x00[j]);   // frames high @ h
        const float l1 = S * (x01[j] + x11[j]);   // frames low  @ h+1
        const float g1 = S * (x11[j] - x01[j]);   // frames high @ h+1
        const float l2 = S * (x02[j] + x12[j]);   // frames low  @ h+2
        const float g2 = S * (x12[j] - x02[j]);   // frames high @ h+2
        LL0[j] = S * (l0 + l1);  LH0[j] = S * (l1 - l0);
        HL0[j] = S * (g0 + g1);  HH0[j] = S * (g1 - g0);
        LL1[j] = S * (l1 + l2);  LH1[j] = S * (l2 - l1);
        HL1[j] = S * (g1 + g2);  HH1[j] = S * (g2 - g1);
    }

    // ---- width neighbor (w+4) from lane+1; lane 63 -> right zero pad ----
    const float nLL0 = __shfl_down(LL0[0], 1);
    const float nLH0 = __shfl_down(LH0[0], 1);
    const float nHL0 = __shfl_down(HL0[0], 1);
    const float nHH0 = __shfl_down(HH0[0], 1);
    const float nLL1 = __shfl_down(LL1[0], 1);
    const float nLH1 = __shfl_down(LH1[0], 1);
    const float nHL1 = __shfl_down(HL1[0], 1);
    const float nHH1 = __shfl_down(HH1[0], 1);
    const bool last = (lane == 63);
    LL0[4] = last ? 0.f : nLL0;  LH0[4] = last ? 0.f : nLH0;
    HL0[4] = last ? 0.f : nHL0;  HH0[4] = last ? 0.f : nHH0;
    LL1[4] = last ? 0.f : nLL1;  LH1[4] = last ? 0.f : nLH1;
    HL1[4] = last ? 0.f : nHL1;  HH1[4] = last ? 0.f : nHH1;

    // ---- width stage + stores: per stream, 2 adjacent 1KB-contiguous wave stores ----
    const size_t rowOff = ((size_t)h) * 256 + w;
    float* lllDst = out + ((size_t)(nc * 15 + f)) * PLANE + rowOff;
    nt_store(lllDst,       pack_lo(LL0));   // LLL row h
    nt_store(lllDst + 256, pack_lo(LL1));   // LLL row h+1

    float* dbase = out + LLL_ELEMS +
                   ((size_t)nc * 105 + f) * PLANE + rowOff;
    const size_t kStride = (size_t)15 * PLANE;
    nt_store(dbase + 0 * kStride,       pack_hi(LL0));   // LLH
    nt_store(dbase + 0 * kStride + 256, pack_hi(LL1));
    nt_store(dbase + 1 * kStride,       pack_lo(LH0));   // LHL
    nt_store(dbase + 1 * kStride + 256, pack_lo(LH1));
    nt_store(dbase + 2 * kStride,       pack_hi(LH0));   // LHH
    nt_store(dbase + 2 * kStride + 256, pack_hi(LH1));
    nt_store(dbase + 3 * kStride,       pack_lo(HL0));   // HLL
    nt_store(dbase + 3 * kStride + 256, pack_lo(HL1));
    nt_store(dbase + 4 * kStride,       pack_hi(HL0));   // HLH
    nt_store(dbase + 4 * kStride + 256, pack_hi(HL1));
    nt_store(dbase + 5 * kStride,       pack_lo(HH0));   // HHL
    nt_store(dbase + 5 * kStride + 256, pack_lo(HH1));
    nt_store(dbase + 6 * kStride,       pack_hi(HH0));   // HHH
    nt_store(dbase + 6 * kStride + 256, pack_hi(HH1));
}

extern "C" void kernel_launch(void* const* d_in, const int* in_sizes, int n_in,
                              void* d_out, int out_size, void* d_ws, size_t ws_size,
                              hipStream_t stream) {
    const float* x = (const float*)d_in[0];
    float* out = (float*)d_out;
    // 11520 pair-rows * 64 lanes = 737,280 threads = 2880 blocks of 256 (exact)
    haar3d_kernel<<<dim3(2880), dim3(256), 0, stream>>>(x, out);
}